// Round 1
// baseline (1348.480 us; speedup 1.0000x reference)
//
#include <hip/hip_runtime.h>
#include <hip/hip_fp16.h>

typedef __attribute__((ext_vector_type(8))) short short8;
typedef __attribute__((ext_vector_type(4))) float f32x4;
typedef unsigned short ushort_t;
typedef unsigned int uint_t;

#define B_SZ 32
#define T_SZ 4096
#define D_IN 256
#define H_SZ 256
#define M_SZ (B_SZ * T_SZ)  // 131072

__device__ __forceinline__ ushort_t f2bf(float f) {
  unsigned int u = __float_as_uint(f);
  unsigned int r = (u + 0x7FFFu + ((u >> 16) & 1u)) >> 16;
  return (ushort_t)r;
}

__device__ __forceinline__ float sigmoidf_(float xv) {
  float e = __expf(-fabsf(xv));
  float s = 1.0f / (1.0f + e);
  return xv >= 0.0f ? s : 1.0f - s;
}

// ---------------------------------------------------------------------------
// Kernel 1: pack W'' = interleaved (Wz,Wh by 16-col groups) into bf16, laid
// out EXACTLY as the GEMM's per-kstep LDS image (granule = 16B = 8 bf16),
// including the XOR bank-conflict swizzle, so global_load_lds stages linearly.
// Layout: granule index g in [0, 8*2048): ks = g>>11, gi = g&2047,
//   n = gi>>2 (0..511 = interleaved output col), cs = gi&3 (swizzled k-chunk),
//   real chunk c = cs ^ (n&3), holds W''[n][ks*32 + c*8 .. +7].
// W''[n] -> gate = (n>>4)&1 (0=Wz,1=Wh), h = (n>>5)*16 + (n&15).
// ---------------------------------------------------------------------------
__global__ void prep_w(const float* __restrict__ Wz, const float* __restrict__ Wh,
                       ushort_t* __restrict__ wsB) {
  int g = blockIdx.x * 256 + threadIdx.x;
  if (g >= 8 * 2048) return;
  int ks = g >> 11;
  int gi = g & 2047;
  int n = gi >> 2;
  int cs = gi & 3;
  int c = cs ^ (n & 3);
  int h = (n >> 5) * 16 + (n & 15);
  const float* W = ((n >> 4) & 1) ? Wh : Wz;
  const float* src = W + (size_t)h * D_IN + ks * 32 + c * 8;
  ushort_t* dst = wsB + (size_t)g * 8;
#pragma unroll
  for (int j = 0; j < 8; ++j) dst[j] = f2bf(src[j]);
}

// ---------------------------------------------------------------------------
// Kernel 2: bf16 MFMA GEMM (both gates at once, N=512 interleaved) fused with
// the elementwise gate math; writes packed half2(a, v) per (row=b*T+t, h).
// Block tile: BM=128 x BN=512, BK=32, 8 ksteps (K=256). 512 threads = 8 waves
// in a 2(M) x 4(N) grid; wave tile 64x128 -> acc[4][8] f32x4.
// A: reg-staged fp32->bf16 with T14 split (load early, ds_write after MFMAs).
// B: global_load_lds width=16 from pre-swizzled wsB.
// ---------------------------------------------------------------------------
__global__ __launch_bounds__(512, 2) void gemm_av(
    const float* __restrict__ x, const ushort_t* __restrict__ wsB,
    const float* __restrict__ bz, const float* __restrict__ bh,
    uint_t* __restrict__ av) {
  __shared__ __align__(16) unsigned char lds[81920];
  ushort_t* As = (ushort_t*)lds;                  // 2 x 8192 B
  ushort_t* Bs = (ushort_t*)(lds + 16384);        // 2 x 32768 B

  const int tid = threadIdx.x;
  const int lane = tid & 63;
  const int wid = tid >> 6;
  const int wr = wid >> 2;   // 0..1
  const int wc = wid & 3;    // 0..3
  const int m0 = blockIdx.x * 128;

  const int arow = tid >> 2;     // 0..127
  const int ac = tid & 3;        // 0..3 (k-chunk of 8 floats)
  const int agran = arow * 4 + (ac ^ (arow & 3));  // swizzled granule
  const float* asrc = x + (size_t)(m0 + arow) * D_IN + ac * 8;

  f32x4 acc[4][8];
#pragma unroll
  for (int rt = 0; rt < 4; ++rt)
#pragma unroll
    for (int ct = 0; ct < 8; ++ct) {
      f32x4 z4 = {0.f, 0.f, 0.f, 0.f};
      acc[rt][ct] = z4;
    }

  // ---- prologue: stage kstep 0 into buffer 0 ----
  {
    // B: async global->LDS (1KB per wave per call, 4 calls)
    const ushort_t* bsrc = wsB + 0 * 16384 + wid * 2048 + lane * 8;
    ushort_t* bdst = Bs + 0 * 16384 + wid * 2048;
#pragma unroll
    for (int cc = 0; cc < 4; ++cc) {
      __builtin_amdgcn_global_load_lds(
          (const __attribute__((address_space(1))) void*)(bsrc + cc * 512),
          (__attribute__((address_space(3))) void*)(bdst + cc * 512), 16, 0, 0);
    }
    // A: reg-stage + cvt + ds_write
    float4 f0 = *(const float4*)(asrc);
    float4 f1 = *(const float4*)(asrc + 4);
    short8 vfr;
    ushort_t* vp = (ushort_t*)&vfr;
    vp[0] = f2bf(f0.x); vp[1] = f2bf(f0.y); vp[2] = f2bf(f0.z); vp[3] = f2bf(f0.w);
    vp[4] = f2bf(f1.x); vp[5] = f2bf(f1.y); vp[6] = f2bf(f1.z); vp[7] = f2bf(f1.w);
    *(short8*)(As + agran * 8) = vfr;
  }
  __syncthreads();

#pragma unroll
  for (int ks = 0; ks < 8; ++ks) {
    const int cur = ks & 1;
    // 1. LDS -> register fragments (current buffer)
    short8 afr[4], bfr[8];
#pragma unroll
    for (int rt = 0; rt < 4; ++rt) {
      int row = wr * 64 + rt * 16 + (lane & 15);
      int gran = row * 4 + ((lane >> 4) ^ (row & 3));
      afr[rt] = *(const short8*)(As + cur * 4096 + gran * 8);
    }
#pragma unroll
    for (int ct = 0; ct < 8; ++ct) {
      int n = wc * 128 + ct * 16 + (lane & 15);
      int gran = n * 4 + ((lane >> 4) ^ (n & 3));
      bfr[ct] = *(const short8*)(Bs + cur * 16384 + gran * 8);
    }
    // 2. issue next-tile staging loads (latency hides under MFMAs)
    float4 nf0, nf1;
    if (ks < 7) {
      const ushort_t* bsrc = wsB + (size_t)(ks + 1) * 16384 + wid * 2048 + lane * 8;
      ushort_t* bdst = Bs + (cur ^ 1) * 16384 + wid * 2048;
#pragma unroll
      for (int cc = 0; cc < 4; ++cc) {
        __builtin_amdgcn_global_load_lds(
            (const __attribute__((address_space(1))) void*)(bsrc + cc * 512),
            (__attribute__((address_space(3))) void*)(bdst + cc * 512), 16, 0, 0);
      }
      nf0 = *(const float4*)(asrc + (ks + 1) * 32);
      nf1 = *(const float4*)(asrc + (ks + 1) * 32 + 4);
    }
    // 3. MFMAs
#pragma unroll
    for (int rt = 0; rt < 4; ++rt)
#pragma unroll
      for (int ct = 0; ct < 8; ++ct)
        acc[rt][ct] = __builtin_amdgcn_mfma_f32_16x16x32_bf16(
            afr[rt], bfr[ct], acc[rt][ct], 0, 0, 0);
    // 4. A write-late (waits its own vmcnt, after compute)
    if (ks < 7) {
      short8 vfr;
      ushort_t* vp = (ushort_t*)&vfr;
      vp[0] = f2bf(nf0.x); vp[1] = f2bf(nf0.y); vp[2] = f2bf(nf0.z); vp[3] = f2bf(nf0.w);
      vp[4] = f2bf(nf1.x); vp[5] = f2bf(nf1.y); vp[6] = f2bf(nf1.z); vp[7] = f2bf(nf1.w);
      *(short8*)(As + (cur ^ 1) * 4096 + agran * 8) = vfr;
    }
    __syncthreads();
  }

  // ---- epilogue: gate math, pack half2(a,v) ----
  const int col16 = lane & 15;
  const int rgrp = lane >> 4;
#pragma unroll
  for (int i = 0; i < 4; ++i) {
    int hh = (wc * 4 + i) * 16 + col16;
    float bzv = bz[hh];
    float bhv = bh[hh];
#pragma unroll
    for (int rt = 0; rt < 4; ++rt) {
#pragma unroll
      for (int j = 0; j < 4; ++j) {
        int row = m0 + wr * 64 + rt * 16 + rgrp * 4 + j;
        float kv = acc[rt][2 * i][j] + bzv;
        float pv = acc[rt][2 * i + 1][j] + bhv;
        float a = sigmoidf_(-kv);       // 1 - sigmoid(k)
        float z = 1.0f - a;             // sigmoid(k)
        float gg = (pv >= 0.0f) ? (pv + 0.5f) : sigmoidf_(pv);
        float vv = z * gg;
        uint_t pk = (uint_t)__half_as_ushort(__float2half_rn(a)) |
                    ((uint_t)__half_as_ushort(__float2half_rn(vv)) << 16);
        av[(size_t)row * H_SZ + hh] = pk;
      }
    }
  }
}

// ---------------------------------------------------------------------------
// Kernel 3: sequential scan h[t] = a*h[t-1] + v over T per (b,h).
// 128 blocks x 64 threads; each lane owns one h (coalesced 256B/wave/step).
// Depth-32 register prefetch ring to cover HBM latency.
// NOTE: av may alias out (in-place); per-element the load of av[t] is
// data-dependency-ordered before the store of out[t].
// ---------------------------------------------------------------------------
__global__ __launch_bounds__(64) void scan_seq(const float* __restrict__ h0,
                                               const uint_t* av, float* out) {
  const int b = blockIdx.x >> 2;
  const int hg = blockIdx.x & 3;
  const int h = hg * 64 + threadIdx.x;

  float hc;
  {
    float v0 = h0[b * H_SZ + h];
    hc = (v0 >= 0.0f) ? (v0 + 0.5f) : sigmoidf_(v0);
  }

  const uint_t* p = av + (size_t)b * T_SZ * H_SZ + h;
  float* o = out + (size_t)b * T_SZ * H_SZ + h;

  uint_t buf[32];
#pragma unroll
  for (int d = 0; d < 32; ++d) buf[d] = p[(size_t)d * H_SZ];

  for (int t0 = 0; t0 < T_SZ; t0 += 32) {
#pragma unroll
    for (int d = 0; d < 32; ++d) {
      int t = t0 + d;
      uint_t pk = buf[d];
      int tn = t + 32;
      if (tn < T_SZ) buf[d] = p[(size_t)tn * H_SZ];
      float a = __half2float(__ushort_as_half((ushort_t)(pk & 0xFFFFu)));
      float v = __half2float(__ushort_as_half((ushort_t)(pk >> 16)));
      hc = fmaf(a, hc, v);
      o[(size_t)t * H_SZ] = hc;
    }
  }
}

extern "C" void kernel_launch(void* const* d_in, const int* in_sizes, int n_in,
                              void* d_out, int out_size, void* d_ws, size_t ws_size,
                              hipStream_t stream) {
  const float* x  = (const float*)d_in[0];
  const float* h0 = (const float*)d_in[1];
  const float* Wz = (const float*)d_in[2];
  const float* bz = (const float*)d_in[3];
  const float* Wh = (const float*)d_in[4];
  const float* bh = (const float*)d_in[5];
  float* out = (float*)d_out;

  ushort_t* wsB = (ushort_t*)d_ws;  // 256 KiB packed weights
  const size_t avOff = 262144;
  const size_t avBytes = (size_t)M_SZ * H_SZ * 4;
  uint_t* av;
  if (ws_size >= avOff + avBytes) {
    av = (uint_t*)((char*)d_ws + avOff);
  } else {
    av = (uint_t*)d_out;  // in-place fallback: scan reads av[t] before writing h[t]
  }

  prep_w<<<64, 256, 0, stream>>>(Wz, Wh, wsB);
  gemm_av<<<M_SZ / 128, 512, 0, stream>>>(x, wsB, bz, bh, av);
  scan_seq<<<B_SZ * 4, 64, 0, stream>>>(h0, av, out);
}

// Round 2
// 182.205 us; speedup vs baseline: 7.4009x; 7.4009x over previous
//
#include <hip/hip_runtime.h>
#include <hip/hip_fp16.h>

typedef __attribute__((ext_vector_type(8))) short short8;
typedef __attribute__((ext_vector_type(4))) float f32x4;
typedef unsigned short ushort_t;
typedef unsigned int uint_t;

#define B_SZ 32
#define T_SZ 4096
#define D_IN 256
#define H_SZ 256
#define M_SZ (B_SZ * T_SZ)  // 131072
#define CHUNK 64
#define NCHUNK (T_SZ / CHUNK)  // 64

__device__ __forceinline__ ushort_t f2bf(float f) {
  unsigned int u = __float_as_uint(f);
  unsigned int r = (u + 0x7FFFu + ((u >> 16) & 1u)) >> 16;
  return (ushort_t)r;
}

__device__ __forceinline__ float sigmoidf_(float xv) {
  float e = __expf(-fabsf(xv));
  float s = 1.0f / (1.0f + e);
  return xv >= 0.0f ? s : 1.0f - s;
}

__device__ __forceinline__ float unpack_lo(uint_t pk) {
  return __half2float(__ushort_as_half((ushort_t)(pk & 0xFFFFu)));
}
__device__ __forceinline__ float unpack_hi(uint_t pk) {
  return __half2float(__ushort_as_half((ushort_t)(pk >> 16)));
}

// ---------------------------------------------------------------------------
// Kernel 1: pack W'' = interleaved (Wz,Wh by 16-col groups) into bf16, laid
// out EXACTLY as the GEMM's per-kstep LDS image (granule = 16B = 8 bf16),
// including the XOR bank-conflict swizzle, so global_load_lds stages linearly.
// ---------------------------------------------------------------------------
__global__ void prep_w(const float* __restrict__ Wz, const float* __restrict__ Wh,
                       ushort_t* __restrict__ wsB) {
  int g = blockIdx.x * 256 + threadIdx.x;
  if (g >= 8 * 2048) return;
  int ks = g >> 11;
  int gi = g & 2047;
  int n = gi >> 2;
  int cs = gi & 3;
  int c = cs ^ (n & 3);
  int h = (n >> 5) * 16 + (n & 15);
  const float* W = ((n >> 4) & 1) ? Wh : Wz;
  const float* src = W + (size_t)h * D_IN + ks * 32 + c * 8;
  ushort_t* dst = wsB + (size_t)g * 8;
#pragma unroll
  for (int j = 0; j < 8; ++j) dst[j] = f2bf(src[j]);
  (void)ks;
}

// ---------------------------------------------------------------------------
// Kernel 2: bf16 MFMA GEMM (both gates at once, N=512 interleaved) fused with
// the elementwise gate math; writes packed half2(a, v) per (row=b*T+t, h).
// ---------------------------------------------------------------------------
__global__ __launch_bounds__(512, 2) void gemm_av(
    const float* __restrict__ x, const ushort_t* __restrict__ wsB,
    const float* __restrict__ bz, const float* __restrict__ bh,
    uint_t* __restrict__ av) {
  __shared__ __align__(16) unsigned char lds[81920];
  ushort_t* As = (ushort_t*)lds;                  // 2 x 8192 B
  ushort_t* Bs = (ushort_t*)(lds + 16384);        // 2 x 32768 B

  const int tid = threadIdx.x;
  const int lane = tid & 63;
  const int wid = tid >> 6;
  const int wr = wid >> 2;   // 0..1
  const int wc = wid & 3;    // 0..3
  const int m0 = blockIdx.x * 128;

  const int arow = tid >> 2;     // 0..127
  const int ac = tid & 3;        // 0..3 (k-chunk of 8 floats)
  const int agran = arow * 4 + (ac ^ (arow & 3));  // swizzled granule
  const float* asrc = x + (size_t)(m0 + arow) * D_IN + ac * 8;

  f32x4 acc[4][8];
#pragma unroll
  for (int rt = 0; rt < 4; ++rt)
#pragma unroll
    for (int ct = 0; ct < 8; ++ct) {
      f32x4 z4 = {0.f, 0.f, 0.f, 0.f};
      acc[rt][ct] = z4;
    }

  // ---- prologue: stage kstep 0 into buffer 0 ----
  {
    const ushort_t* bsrc = wsB + 0 * 16384 + wid * 2048 + lane * 8;
    ushort_t* bdst = Bs + 0 * 16384 + wid * 2048;
#pragma unroll
    for (int cc = 0; cc < 4; ++cc) {
      __builtin_amdgcn_global_load_lds(
          (const __attribute__((address_space(1))) void*)(bsrc + cc * 512),
          (__attribute__((address_space(3))) void*)(bdst + cc * 512), 16, 0, 0);
    }
    float4 f0 = *(const float4*)(asrc);
    float4 f1 = *(const float4*)(asrc + 4);
    short8 vfr;
    ushort_t* vp = (ushort_t*)&vfr;
    vp[0] = f2bf(f0.x); vp[1] = f2bf(f0.y); vp[2] = f2bf(f0.z); vp[3] = f2bf(f0.w);
    vp[4] = f2bf(f1.x); vp[5] = f2bf(f1.y); vp[6] = f2bf(f1.z); vp[7] = f2bf(f1.w);
    *(short8*)(As + agran * 8) = vfr;
  }
  __syncthreads();

#pragma unroll
  for (int ks = 0; ks < 8; ++ks) {
    const int cur = ks & 1;
    short8 afr[4], bfr[8];
#pragma unroll
    for (int rt = 0; rt < 4; ++rt) {
      int row = wr * 64 + rt * 16 + (lane & 15);
      int gran = row * 4 + ((lane >> 4) ^ (row & 3));
      afr[rt] = *(const short8*)(As + cur * 4096 + gran * 8);
    }
#pragma unroll
    for (int ct = 0; ct < 8; ++ct) {
      int n = wc * 128 + ct * 16 + (lane & 15);
      int gran = n * 4 + ((lane >> 4) ^ (n & 3));
      bfr[ct] = *(const short8*)(Bs + cur * 16384 + gran * 8);
    }
    float4 nf0, nf1;
    if (ks < 7) {
      const ushort_t* bsrc = wsB + (size_t)(ks + 1) * 16384 + wid * 2048 + lane * 8;
      ushort_t* bdst = Bs + (cur ^ 1) * 16384 + wid * 2048;
#pragma unroll
      for (int cc = 0; cc < 4; ++cc) {
        __builtin_amdgcn_global_load_lds(
            (const __attribute__((address_space(1))) void*)(bsrc + cc * 512),
            (__attribute__((address_space(3))) void*)(bdst + cc * 512), 16, 0, 0);
      }
      nf0 = *(const float4*)(asrc + (ks + 1) * 32);
      nf1 = *(const float4*)(asrc + (ks + 1) * 32 + 4);
    }
#pragma unroll
    for (int rt = 0; rt < 4; ++rt)
#pragma unroll
      for (int ct = 0; ct < 8; ++ct)
        acc[rt][ct] = __builtin_amdgcn_mfma_f32_16x16x32_bf16(
            afr[rt], bfr[ct], acc[rt][ct], 0, 0, 0);
    if (ks < 7) {
      short8 vfr;
      ushort_t* vp = (ushort_t*)&vfr;
      vp[0] = f2bf(nf0.x); vp[1] = f2bf(nf0.y); vp[2] = f2bf(nf0.z); vp[3] = f2bf(nf0.w);
      vp[4] = f2bf(nf1.x); vp[5] = f2bf(nf1.y); vp[6] = f2bf(nf1.z); vp[7] = f2bf(nf1.w);
      *(short8*)(As + (cur ^ 1) * 4096 + agran * 8) = vfr;
    }
    __syncthreads();
  }

  // ---- epilogue: gate math, pack half2(a,v) ----
  const int col16 = lane & 15;
  const int rgrp = lane >> 4;
#pragma unroll
  for (int i = 0; i < 4; ++i) {
    int hh = (wc * 4 + i) * 16 + col16;
    float bzv = bz[hh];
    float bhv = bh[hh];
#pragma unroll
    for (int rt = 0; rt < 4; ++rt) {
#pragma unroll
      for (int j = 0; j < 4; ++j) {
        int row = m0 + wr * 64 + rt * 16 + rgrp * 4 + j;
        float kv = acc[rt][2 * i][j] + bzv;
        float pv = acc[rt][2 * i + 1][j] + bhv;
        float a = sigmoidf_(-kv);       // 1 - sigmoid(k)
        float z = 1.0f - a;             // sigmoid(k)
        float gg = (pv >= 0.0f) ? (pv + 0.5f) : sigmoidf_(pv);
        float vv = z * gg;
        uint_t pk = (uint_t)__half_as_ushort(__float2half_rn(a)) |
                    ((uint_t)__half_as_ushort(__float2half_rn(vv)) << 16);
        av[(size_t)row * H_SZ + hh] = pk;
      }
    }
  }
}

// ---------------------------------------------------------------------------
// Two-level scan. h[t] = a*h[t-1] + v is an associative affine composition:
// a CHUNK-step window reduces to (A = prod a, V) with h_out = A*h_in + V.
//
// Phase 1: per (b, chunk), all 256 h in one block: compose the 64 steps.
//          2048 blocks x 256 thr = 8192 waves -> latency fully hidden.
// ---------------------------------------------------------------------------
__global__ __launch_bounds__(256) void chunk_reduce(
    const uint_t* __restrict__ av, float2* __restrict__ cAV) {
  const int b = blockIdx.x >> 6;
  const int c = blockIdx.x & 63;
  const int h = threadIdx.x;
  const uint_t* p = av + ((size_t)b * T_SZ + c * CHUNK) * H_SZ + h;

  uint_t buf[CHUNK];
#pragma unroll
  for (int s = 0; s < CHUNK; ++s) buf[s] = p[(size_t)s * H_SZ];

  float A = 1.0f, V = 0.0f;
#pragma unroll
  for (int s = 0; s < CHUNK; ++s) {
    float a = unpack_lo(buf[s]);
    float v = unpack_hi(buf[s]);
    A = a * A;
    V = fmaf(a, V, v);
  }
  float2 r; r.x = A; r.y = V;
  cAV[((size_t)b * NCHUNK + c) * H_SZ + h] = r;
}

// ---------------------------------------------------------------------------
// Phase 2: per (b,h): sequentially compose chunk summaries from g(h0),
// writing the INCOMING h for each chunk. 32 blocks x 256 thr; tiny.
// ---------------------------------------------------------------------------
__global__ __launch_bounds__(256) void chunk_carry(
    const float* __restrict__ h0, const float2* __restrict__ cAV,
    float* __restrict__ hb) {
  const int b = blockIdx.x;
  const int h = threadIdx.x;
  float v0 = h0[b * H_SZ + h];
  float hc = (v0 >= 0.0f) ? (v0 + 0.5f) : sigmoidf_(v0);

  const float2* p = cAV + (size_t)b * NCHUNK * H_SZ + h;
  float* o = hb + (size_t)b * NCHUNK * H_SZ + h;

  float2 buf[NCHUNK];
#pragma unroll
  for (int c = 0; c < NCHUNK; ++c) buf[c] = p[(size_t)c * H_SZ];

#pragma unroll
  for (int c = 0; c < NCHUNK; ++c) {
    o[(size_t)c * H_SZ] = hc;
    hc = fmaf(buf[c].x, hc, buf[c].y);
  }
}

// ---------------------------------------------------------------------------
// Phase 3: per (b, chunk): start from carry, re-scan av, write fp32 out.
// av may alias out (in-place fallback): each thread's 64 loads strictly
// precede its 64 stores to the same addresses; other threads' elements are
// disjoint. No __restrict__ on av/out so program order is preserved.
// ---------------------------------------------------------------------------
__global__ __launch_bounds__(256) void chunk_scan_out(
    const uint_t* av, const float* __restrict__ hb, float* out) {
  const int b = blockIdx.x >> 6;
  const int c = blockIdx.x & 63;
  const int h = threadIdx.x;

  float hc = hb[((size_t)b * NCHUNK + c) * H_SZ + h];
  const uint_t* p = av + ((size_t)b * T_SZ + c * CHUNK) * H_SZ + h;
  float* o = out + ((size_t)b * T_SZ + c * CHUNK) * H_SZ + h;

  uint_t buf[CHUNK];
#pragma unroll
  for (int s = 0; s < CHUNK; ++s) buf[s] = p[(size_t)s * H_SZ];

#pragma unroll
  for (int s = 0; s < CHUNK; ++s) {
    float a = unpack_lo(buf[s]);
    float v = unpack_hi(buf[s]);
    hc = fmaf(a, hc, v);
    o[(size_t)s * H_SZ] = hc;
  }
}

// ---------------------------------------------------------------------------
// Fallback: old fully-sequential scan (only if ws is too small for summaries).
// ---------------------------------------------------------------------------
__global__ __launch_bounds__(64) void scan_seq(const float* __restrict__ h0,
                                               const uint_t* av, float* out) {
  const int b = blockIdx.x >> 2;
  const int hg = blockIdx.x & 3;
  const int h = hg * 64 + threadIdx.x;

  float v0 = h0[b * H_SZ + h];
  float hc = (v0 >= 0.0f) ? (v0 + 0.5f) : sigmoidf_(v0);

  const uint_t* p = av + (size_t)b * T_SZ * H_SZ + h;
  float* o = out + (size_t)b * T_SZ * H_SZ + h;

  uint_t buf[32];
#pragma unroll
  for (int d = 0; d < 32; ++d) buf[d] = p[(size_t)d * H_SZ];

  for (int t0 = 0; t0 < T_SZ; t0 += 32) {
#pragma unroll
    for (int d = 0; d < 32; ++d) {
      int t = t0 + d;
      uint_t pk = buf[d];
      int tn = t + 32;
      if (tn < T_SZ) buf[d] = p[(size_t)tn * H_SZ];
      hc = fmaf(unpack_lo(pk), hc, unpack_hi(pk));
      o[(size_t)t * H_SZ] = hc;
    }
  }
}

extern "C" void kernel_launch(void* const* d_in, const int* in_sizes, int n_in,
                              void* d_out, int out_size, void* d_ws, size_t ws_size,
                              hipStream_t stream) {
  const float* x  = (const float*)d_in[0];
  const float* h0 = (const float*)d_in[1];
  const float* Wz = (const float*)d_in[2];
  const float* bz = (const float*)d_in[3];
  const float* Wh = (const float*)d_in[4];
  const float* bh = (const float*)d_in[5];
  float* out = (float*)d_out;

  // ws layout: [wsB 256K][cAV 4M][hb 2M][pad][av 134M if it fits]
  const size_t wsBBytes = 262144;
  const size_t cavBytes = (size_t)B_SZ * NCHUNK * H_SZ * 8;   // 4 MiB
  const size_t hbBytes  = (size_t)B_SZ * NCHUNK * H_SZ * 4;   // 2 MiB
  const size_t avOff    = 8388608;
  const size_t avBytes  = (size_t)M_SZ * H_SZ * 4;            // 134 MiB

  ushort_t* wsB = (ushort_t*)d_ws;
  float2* cAV = (float2*)((char*)d_ws + wsBBytes);
  float* hb   = (float*)((char*)d_ws + wsBBytes + cavBytes);

  const bool haveSummaries = ws_size >= wsBBytes + cavBytes + hbBytes;
  uint_t* av;
  if (ws_size >= avOff + avBytes) {
    av = (uint_t*)((char*)d_ws + avOff);
  } else {
    av = (uint_t*)d_out;  // in-place: reads precede writes per element
  }

  prep_w<<<64, 256, 0, stream>>>(Wz, Wh, wsB);
  gemm_av<<<M_SZ / 128, 512, 0, stream>>>(x, wsB, bz, bh, av);
  if (haveSummaries) {
    chunk_reduce<<<B_SZ * NCHUNK, 256, 0, stream>>>(av, cAV);
    chunk_carry<<<B_SZ, 256, 0, stream>>>(h0, cAV, hb);
    chunk_scan_out<<<B_SZ * NCHUNK, 256, 0, stream>>>(av, hb, out);
  } else {
    scan_seq<<<B_SZ * 4, 64, 0, stream>>>(h0, av, out);
  }
}

// Round 3
// 174.667 us; speedup vs baseline: 7.7203x; 1.0432x over previous
//
#include <hip/hip_runtime.h>
#include <hip/hip_fp16.h>

typedef __attribute__((ext_vector_type(8))) short short8;
typedef __attribute__((ext_vector_type(4))) float f32x4;
typedef unsigned short ushort_t;
typedef unsigned int uint_t;

#define B_SZ 32
#define T_SZ 4096
#define D_IN 256
#define H_SZ 256
#define M_SZ (B_SZ * T_SZ)  // 131072
#define CHUNK 64
#define NCHUNK (T_SZ / CHUNK)  // 64

__device__ __forceinline__ ushort_t f2bf(float f) {
  unsigned int u = __float_as_uint(f);
  unsigned int r = (u + 0x7FFFu + ((u >> 16) & 1u)) >> 16;
  return (ushort_t)r;
}

__device__ __forceinline__ float sigmoidf_(float xv) {
  float e = __expf(-fabsf(xv));
  float s = 1.0f / (1.0f + e);
  return xv >= 0.0f ? s : 1.0f - s;
}

__device__ __forceinline__ float unpack_lo(uint_t pk) {
  return __half2float(__ushort_as_half((ushort_t)(pk & 0xFFFFu)));
}
__device__ __forceinline__ float unpack_hi(uint_t pk) {
  return __half2float(__ushort_as_half((ushort_t)(pk >> 16)));
}

// ---------------------------------------------------------------------------
// Kernel 1: pack W'' (Wz,Wh interleaved by 16-col groups) into bf16 in the
// GEMM's exact per-kstep LDS image, GRANULE-MAJOR: granule index within a
// kstep = c*512 + n  (c = 16B k-chunk 0..3, n = interleaved col 0..511).
// Granule-major means the GEMM's 16-lane row-groups read contiguous 16B
// granules (2 lanes/bank aliasing only = conflict-free), so no XOR swizzle
// is needed on either side and global_load_lds stages linearly.
// W''[n] -> gate = (n>>4)&1 (0=Wz,1=Wh), h = (n>>5)*16 + (n&15).
// ---------------------------------------------------------------------------
__global__ void prep_w(const float* __restrict__ Wz, const float* __restrict__ Wh,
                       ushort_t* __restrict__ wsB) {
  int g = blockIdx.x * 256 + threadIdx.x;  // 16384 granules total
  if (g >= 8 * 2048) return;
  int ks = g >> 11;
  int r = g & 2047;
  int c = r >> 9;        // 0..3
  int n = r & 511;       // 0..511
  int h = (n >> 5) * 16 + (n & 15);
  const float* W = ((n >> 4) & 1) ? Wh : Wz;
  const float* src = W + (size_t)h * D_IN + ks * 32 + c * 8;
  ushort_t* dst = wsB + (size_t)g * 8;
#pragma unroll
  for (int j = 0; j < 8; ++j) dst[j] = f2bf(src[j]);
}

// ---------------------------------------------------------------------------
// Kernel 2: bf16 MFMA GEMM (both gates, N=512 interleaved) fused with gate
// math; writes packed half2(a, v) per (row=b*T+t, h).
// Block tile BM=64 x BN=512, BK=32, 8 ksteps. 512 threads = 8 waves, 1(M)x8(N)
// -> wave tile 64x64, acc[4][4]. LDS 72KB (A 2x4K, B 2x32K) -> 2 blocks/CU.
// A: waves 0-3 reg-stage fp32->bf16 (T14: load early / write late).
// B: global_load_lds width=16 from granule-major wsB (L2-resident).
// ---------------------------------------------------------------------------
__global__ __launch_bounds__(512, 4) void gemm_av(
    const float* __restrict__ x, const ushort_t* __restrict__ wsB,
    const float* __restrict__ bz, const float* __restrict__ bh,
    uint_t* __restrict__ av) {
  __shared__ __align__(16) unsigned char lds[73728];
  ushort_t* As = (ushort_t*)lds;                  // 2 x 4096 B  (2048 el/buf)
  ushort_t* Bs = (ushort_t*)(lds + 8192);         // 2 x 32768 B (16384 el/buf)

  const int tid = threadIdx.x;
  const int lane = tid & 63;
  const int wid = tid >> 6;         // 0..7 = N-group
  const int m0 = blockIdx.x * 64;

  // A-stage mapping (threads 0..255): granule G = g*64 + row, g = 16B k-chunk
  const int a_row = tid & 63;
  const int a_g = tid >> 6;         // valid for tid<256
  const float* asrc = x + (size_t)(m0 + a_row) * D_IN + a_g * 8;

  f32x4 acc[4][4];
#pragma unroll
  for (int rt = 0; rt < 4; ++rt)
#pragma unroll
    for (int ct = 0; ct < 4; ++ct) {
      f32x4 z4 = {0.f, 0.f, 0.f, 0.f};
      acc[rt][ct] = z4;
    }

  // ---- prologue: stage kstep 0 into buffer 0 ----
  {
    const ushort_t* bsrc = wsB + (size_t)wid * 2048 + lane * 8;
    ushort_t* bdst = Bs + wid * 2048;
#pragma unroll
    for (int cc = 0; cc < 4; ++cc) {
      __builtin_amdgcn_global_load_lds(
          (const __attribute__((address_space(1))) void*)(bsrc + cc * 512),
          (__attribute__((address_space(3))) void*)(bdst + cc * 512), 16, 0, 0);
    }
    if (tid < 256) {
      float4 f0 = *(const float4*)(asrc);
      float4 f1 = *(const float4*)(asrc + 4);
      short8 vfr;
      ushort_t* vp = (ushort_t*)&vfr;
      vp[0] = f2bf(f0.x); vp[1] = f2bf(f0.y); vp[2] = f2bf(f0.z); vp[3] = f2bf(f0.w);
      vp[4] = f2bf(f1.x); vp[5] = f2bf(f1.y); vp[6] = f2bf(f1.z); vp[7] = f2bf(f1.w);
      *(short8*)(As + tid * 8) = vfr;
    }
  }
  __syncthreads();

#pragma unroll
  for (int ks = 0; ks < 8; ++ks) {
    const int cur = ks & 1;
    // 1. LDS -> register fragments (granule-major: granule = c*NROWS + idx)
    short8 afr[4], bfr[4];
    {
      const int c = lane >> 4;
      const int r16 = lane & 15;
#pragma unroll
      for (int rt = 0; rt < 4; ++rt) {
        int row = rt * 16 + r16;
        afr[rt] = *(const short8*)(As + cur * 2048 + (c * 64 + row) * 8);
      }
#pragma unroll
      for (int ct = 0; ct < 4; ++ct) {
        int n = wid * 64 + ct * 16 + r16;
        bfr[ct] = *(const short8*)(Bs + cur * 16384 + (c * 512 + n) * 8);
      }
    }
    // 2. issue next-tile staging (latency hides under MFMAs)
    float4 nf0, nf1;
    if (ks < 7) {
      const ushort_t* bsrc = wsB + (size_t)(ks + 1) * 16384 + wid * 2048 + lane * 8;
      ushort_t* bdst = Bs + (cur ^ 1) * 16384 + wid * 2048;
#pragma unroll
      for (int cc = 0; cc < 4; ++cc) {
        __builtin_amdgcn_global_load_lds(
            (const __attribute__((address_space(1))) void*)(bsrc + cc * 512),
            (__attribute__((address_space(3))) void*)(bdst + cc * 512), 16, 0, 0);
      }
      if (tid < 256) {
        nf0 = *(const float4*)(asrc + (ks + 1) * 32);
        nf1 = *(const float4*)(asrc + (ks + 1) * 32 + 4);
      }
    }
    // 3. MFMAs
#pragma unroll
    for (int rt = 0; rt < 4; ++rt)
#pragma unroll
      for (int ct = 0; ct < 4; ++ct)
        acc[rt][ct] = __builtin_amdgcn_mfma_f32_16x16x32_bf16(
            afr[rt], bfr[ct], acc[rt][ct], 0, 0, 0);
    // 4. A write-late (pure reg->LDS after compute)
    if (ks < 7 && tid < 256) {
      short8 vfr;
      ushort_t* vp = (ushort_t*)&vfr;
      vp[0] = f2bf(nf0.x); vp[1] = f2bf(nf0.y); vp[2] = f2bf(nf0.z); vp[3] = f2bf(nf0.w);
      vp[4] = f2bf(nf1.x); vp[5] = f2bf(nf1.y); vp[6] = f2bf(nf1.z); vp[7] = f2bf(nf1.w);
      *(short8*)(As + (cur ^ 1) * 2048 + tid * 8) = vfr;
    }
    __syncthreads();
  }

  // ---- epilogue: gate math, pack half2(a,v) ----
  const int col16 = lane & 15;
  const int rgrp = lane >> 4;
#pragma unroll
  for (int i = 0; i < 2; ++i) {
    int hh = (wid * 2 + i) * 16 + col16;
    float bzv = bz[hh];
    float bhv = bh[hh];
#pragma unroll
    for (int rt = 0; rt < 4; ++rt) {
#pragma unroll
      for (int j = 0; j < 4; ++j) {
        int row = m0 + rt * 16 + rgrp * 4 + j;
        float kv = acc[rt][2 * i][j] + bzv;
        float pv = acc[rt][2 * i + 1][j] + bhv;
        float a = sigmoidf_(-kv);       // 1 - sigmoid(k)
        float z = 1.0f - a;             // sigmoid(k)
        float gg = (pv >= 0.0f) ? (pv + 0.5f) : sigmoidf_(pv);
        float vv = z * gg;
        uint_t pk = (uint_t)__half_as_ushort(__float2half_rn(a)) |
                    ((uint_t)__half_as_ushort(__float2half_rn(vv)) << 16);
        av[(size_t)row * H_SZ + hh] = pk;
      }
    }
  }
}

// ---------------------------------------------------------------------------
// Two-level scan (unchanged from round 2): affine composition per CHUNK.
// ---------------------------------------------------------------------------
__global__ __launch_bounds__(256) void chunk_reduce(
    const uint_t* __restrict__ av, float2* __restrict__ cAV) {
  const int b = blockIdx.x >> 6;
  const int c = blockIdx.x & 63;
  const int h = threadIdx.x;
  const uint_t* p = av + ((size_t)b * T_SZ + c * CHUNK) * H_SZ + h;

  uint_t buf[CHUNK];
#pragma unroll
  for (int s = 0; s < CHUNK; ++s) buf[s] = p[(size_t)s * H_SZ];

  float A = 1.0f, V = 0.0f;
#pragma unroll
  for (int s = 0; s < CHUNK; ++s) {
    float a = unpack_lo(buf[s]);
    float v = unpack_hi(buf[s]);
    A = a * A;
    V = fmaf(a, V, v);
  }
  float2 r; r.x = A; r.y = V;
  cAV[((size_t)b * NCHUNK + c) * H_SZ + h] = r;
}

__global__ __launch_bounds__(256) void chunk_carry(
    const float* __restrict__ h0, const float2* __restrict__ cAV,
    float* __restrict__ hb) {
  const int b = blockIdx.x;
  const int h = threadIdx.x;
  float v0 = h0[b * H_SZ + h];
  float hc = (v0 >= 0.0f) ? (v0 + 0.5f) : sigmoidf_(v0);

  const float2* p = cAV + (size_t)b * NCHUNK * H_SZ + h;
  float* o = hb + (size_t)b * NCHUNK * H_SZ + h;

  float2 buf[NCHUNK];
#pragma unroll
  for (int c = 0; c < NCHUNK; ++c) buf[c] = p[(size_t)c * H_SZ];

#pragma unroll
  for (int c = 0; c < NCHUNK; ++c) {
    o[(size_t)c * H_SZ] = hc;
    hc = fmaf(buf[c].x, hc, buf[c].y);
  }
}

// av may alias out (in-place fallback): per-thread loads strictly precede
// stores to the same addresses; no __restrict__ on av/out.
__global__ __launch_bounds__(256) void chunk_scan_out(
    const uint_t* av, const float* __restrict__ hb, float* out) {
  const int b = blockIdx.x >> 6;
  const int c = blockIdx.x & 63;
  const int h = threadIdx.x;

  float hc = hb[((size_t)b * NCHUNK + c) * H_SZ + h];
  const uint_t* p = av + ((size_t)b * T_SZ + c * CHUNK) * H_SZ + h;
  float* o = out + ((size_t)b * T_SZ + c * CHUNK) * H_SZ + h;

  uint_t buf[CHUNK];
#pragma unroll
  for (int s = 0; s < CHUNK; ++s) buf[s] = p[(size_t)s * H_SZ];

#pragma unroll
  for (int s = 0; s < CHUNK; ++s) {
    float a = unpack_lo(buf[s]);
    float v = unpack_hi(buf[s]);
    hc = fmaf(a, hc, v);
    o[(size_t)s * H_SZ] = hc;
  }
}

// Fallback: fully-sequential scan (only if ws too small for summaries).
__global__ __launch_bounds__(64) void scan_seq(const float* __restrict__ h0,
                                               const uint_t* av, float* out) {
  const int b = blockIdx.x >> 2;
  const int hg = blockIdx.x & 3;
  const int h = hg * 64 + threadIdx.x;

  float v0 = h0[b * H_SZ + h];
  float hc = (v0 >= 0.0f) ? (v0 + 0.5f) : sigmoidf_(v0);

  const uint_t* p = av + (size_t)b * T_SZ * H_SZ + h;
  float* o = out + (size_t)b * T_SZ * H_SZ + h;

  uint_t buf[32];
#pragma unroll
  for (int d = 0; d < 32; ++d) buf[d] = p[(size_t)d * H_SZ];

  for (int t0 = 0; t0 < T_SZ; t0 += 32) {
#pragma unroll
    for (int d = 0; d < 32; ++d) {
      int t = t0 + d;
      uint_t pk = buf[d];
      int tn = t + 32;
      if (tn < T_SZ) buf[d] = p[(size_t)tn * H_SZ];
      hc = fmaf(unpack_lo(pk), hc, unpack_hi(pk));
      o[(size_t)t * H_SZ] = hc;
    }
  }
}

extern "C" void kernel_launch(void* const* d_in, const int* in_sizes, int n_in,
                              void* d_out, int out_size, void* d_ws, size_t ws_size,
                              hipStream_t stream) {
  const float* x  = (const float*)d_in[0];
  const float* h0 = (const float*)d_in[1];
  const float* Wz = (const float*)d_in[2];
  const float* bz = (const float*)d_in[3];
  const float* Wh = (const float*)d_in[4];
  const float* bh = (const float*)d_in[5];
  float* out = (float*)d_out;

  // ws layout: [wsB 256K][cAV 4M][hb 2M][pad][av 134M if it fits]
  const size_t wsBBytes = 262144;
  const size_t cavBytes = (size_t)B_SZ * NCHUNK * H_SZ * 8;   // 4 MiB
  const size_t hbBytes  = (size_t)B_SZ * NCHUNK * H_SZ * 4;   // 2 MiB
  const size_t avOff    = 8388608;
  const size_t avBytes  = (size_t)M_SZ * H_SZ * 4;            // 134 MiB

  ushort_t* wsB = (ushort_t*)d_ws;
  float2* cAV = (float2*)((char*)d_ws + wsBBytes);
  float* hb   = (float*)((char*)d_ws + wsBBytes + cavBytes);

  const bool haveSummaries = ws_size >= wsBBytes + cavBytes + hbBytes;
  uint_t* av;
  if (ws_size >= avOff + avBytes) {
    av = (uint_t*)((char*)d_ws + avOff);
  } else {
    av = (uint_t*)d_out;  // in-place: reads precede writes per element
  }

  prep_w<<<64, 256, 0, stream>>>(Wz, Wh, wsB);
  gemm_av<<<M_SZ / 64, 512, 0, stream>>>(x, wsB, bz, bh, av);
  if (haveSummaries) {
    chunk_reduce<<<B_SZ * NCHUNK, 256, 0, stream>>>(av, cAV);
    chunk_carry<<<B_SZ, 256, 0, stream>>>(h0, cAV, hb);
    chunk_scan_out<<<B_SZ * NCHUNK, 256, 0, stream>>>(av, hb, out);
  } else {
    scan_seq<<<B_SZ * 4, 64, 0, stream>>>(h0, av, out);
  }
}